// Round 5
// baseline (191.888 us; speedup 1.0000x reference)
//
#include <hip/hip_runtime.h>

#define Bc 64
#define Sc 512
#define Dc 768
#define NLc 9
#define Lc 11
#define START (Lc-2)
#define ENDL (Lc-1)
#define NEGC -10000.0f
#define LOG2E 1.4426950408889634f
#define LN2 0.6931471805599453f
#define CHUNK 16
#define NCH (Sc / CHUNK)   // 32

// K1: logits[b,s,l] = dot(inputs[b,s,:], W[l,:]) + bias[l]
// 256-thread blocks, grid=1024. W staged per block (L2-hot re-fetch).
// wave = 4 segments of 16 lanes, one row per segment; 2 quads per wave.
// Full-row prefetch: 12 float4 x-loads issued up front (12 KB/wave in flight),
// then 12 j-steps of 9 LDS float4 + 36 FMA each. launch_bounds(256,3) ->
// VGPR cap ~168: no spill risk (round-3 lesson), 12 waves/CU.
__global__ __launch_bounds__(256, 3) void k_logits(const float* __restrict__ x,
    const float* __restrict__ W, const float* __restrict__ bias,
    float* __restrict__ out)
{
  __shared__ float Wl[NLc * Dc];            // 27648 B
  {
    const float4* Wsrc = reinterpret_cast<const float4*>(W);
    float4* Wdst = reinterpret_cast<float4*>(Wl);
    for (int i = threadIdx.x; i < (NLc * Dc) / 4; i += 256) Wdst[i] = Wsrc[i];
  }
  __syncthreads();
  const int lane = threadIdx.x & 63;
  const int wid  = threadIdx.x >> 6;        // wave in block 0..3
  const int seg  = lane >> 4;               // 0..3
  const int sl   = lane & 15;               // 0..15
  const int gw   = blockIdx.x * 4 + wid;    // global wave id
  const int nwaves = gridDim.x * 4;         // 4096
  const int quads = (Bc * Sc) / 4;          // 8192

#pragma unroll 1
  for (int q = gw; q < quads; q += nwaves) {
    const int row = q * 4 + seg;
    const float4* xr = reinterpret_cast<const float4*>(x + (size_t)row * Dc);
    float4 xv[Dc / 64];                     // 12 float4 = whole row slice
#pragma unroll
    for (int j = 0; j < Dc / 64; j++) xv[j] = xr[j * 16 + sl];
    float acc[NLc];
#pragma unroll
    for (int l = 0; l < NLc; l++) acc[l] = 0.f;
#pragma unroll
    for (int j = 0; j < Dc / 64; j++) {
      const float* wbase = Wl + j * 64 + sl * 4;
#pragma unroll
      for (int l = 0; l < NLc; l++) {
        const float4 wv = *reinterpret_cast<const float4*>(wbase + l * Dc);
        acc[l] = fmaf(xv[j].x, wv.x, acc[l]);
        acc[l] = fmaf(xv[j].y, wv.y, acc[l]);
        acc[l] = fmaf(xv[j].z, wv.z, acc[l]);
        acc[l] = fmaf(xv[j].w, wv.w, acc[l]);
      }
    }
    // butterfly reduce within each 16-lane segment
#pragma unroll
    for (int off = 8; off >= 1; off >>= 1)
#pragma unroll
      for (int l = 0; l < NLc; l++)
        acc[l] += __shfl_xor(acc[l], off, 16);
    // lane sl (<9) writes label sl -> coalesced 36B store per segment
    float v = acc[0];
#pragma unroll
    for (int l = 1; l < NLc; l++) v = (sl == l) ? acc[l] : v;
    if (sl < NLc) out[(size_t)row * NLc + sl] = v + bias[sl];
  }
}

// Phase 1: per (batch, chunk) compute the 11x11 log-semiring transfer matrix.
// Storage: Mout[(b*NCH+c)*121 + j*11 + i] = M[i][j] (exit i, enter j).
// Also zeroes the k_batch completion counter (block 0) each call.
__global__ __launch_bounds__(64) void k_chunk(const float* __restrict__ logits,
    const int* __restrict__ mask, const float* __restrict__ trans,
    float* __restrict__ Mout, unsigned* __restrict__ cnt)
{
  if (blockIdx.x == 0 && threadIdx.x == 0) cnt[0] = 0u;
  const int b = blockIdx.x / NCH;
  const int c = blockIdx.x % NCH;
  const int lane = threadIdx.x;
  __shared__ float Mbuf[2][121];
  __shared__ float Llog[CHUNK][NLc];

  int len = 0;
  for (int t = lane; t < Sc; t += 64) len += mask[b * Sc + t];
#pragma unroll
  for (int off = 32; off >= 1; off >>= 1) len += __shfl_xor(len, off);

  for (int i = lane; i < CHUNK * NLc; i += 64) {
    const int t = i / NLc, l = i % NLc;
    Llog[t][l] = logits[((size_t)b * Sc + c * CHUNK + t) * NLc + l];
  }
  for (int e = lane; e < 121; e += 64) {
    const int i = e % Lc, j = e / Lc;
    Mbuf[0][e] = (i == j) ? 0.f : NEGC;
  }
  const int e1 = lane;          const bool v1 = (e1 < 121);
  const int e2 = lane + 64;     const bool v2 = (e2 < 121);
  const int i1 = v1 ? (e1 % Lc) : 0, j1 = v1 ? (e1 / Lc) : 0;
  const int i2 = v2 ? (e2 % Lc) : 0, j2 = v2 ? (e2 / Lc) : 0;
  float trow1[Lc], trow2[Lc];
#pragma unroll
  for (int k = 0; k < Lc; k++) {
    trow1[k] = trans[i1 * Lc + k];
    trow2[k] = trans[i2 * Lc + k];
  }
  __syncthreads();

  int p = 0;
  for (int t = 0; t < CHUNK; ++t) {
    const int tg = c * CHUNK + t;
    if (tg < len) {   // uniform across block
      const float lg1 = (i1 < NLc) ? Llog[t][i1] : NEGC;
      const float lg2 = (i2 < NLc) ? Llog[t][i2] : NEGC;
      float terms[Lc];
      float m1 = -3.0e38f;
#pragma unroll
      for (int k = 0; k < Lc; k++) {
        terms[k] = trow1[k] + Mbuf[p][j1 * Lc + k];
        m1 = fmaxf(m1, terms[k]);
      }
      float s1 = 0.f;
#pragma unroll
      for (int k = 0; k < Lc; k++) s1 += exp2f((terms[k] - m1) * LOG2E);
      const float n1 = lg1 + m1 + log2f(s1) * LN2;
      float m2 = -3.0e38f;
#pragma unroll
      for (int k = 0; k < Lc; k++) {
        terms[k] = trow2[k] + Mbuf[p][j2 * Lc + k];
        m2 = fmaxf(m2, terms[k]);
      }
      float s2 = 0.f;
#pragma unroll
      for (int k = 0; k < Lc; k++) s2 += exp2f((terms[k] - m2) * LOG2E);
      const float n2 = lg2 + m2 + log2f(s2) * LN2;
      if (v1) Mbuf[p ^ 1][e1] = n1;
      if (v2) Mbuf[p ^ 1][e2] = n2;
      p ^= 1;
    }
    __syncthreads();
  }
  for (int e = lane; e < 121; e += 64)
    Mout[((size_t)b * NCH + c) * 121 + e] = Mbuf[p][e];
}

// K_batch: per batch -- wave 0 runs the 32-step combine (norm), waves 1-3 do
// unary+binary gathers concurrently; then part[b] = u - norm; the last block
// to finish sums all parts and writes the loss (agent-scope atomics for
// cross-XCD coherence, G16).
__global__ __launch_bounds__(256) void k_batch(const float* __restrict__ logits,
    const int* __restrict__ mask, const int* __restrict__ labels,
    const float* __restrict__ trans, const float* __restrict__ Min,
    float* __restrict__ part, unsigned* __restrict__ cnt,
    float* __restrict__ out)
{
  const int b = blockIdx.x;
  const int tid = threadIdx.x;
  const int wid = tid >> 6;
  const int lane = tid & 63;
  const int sl = lane & 15;
  __shared__ float Ms[NCH * 121];
  __shared__ int   ls[4];
  __shared__ float fs[4];
  __shared__ int   len_sh;
  __shared__ float norm_sh;
  __shared__ int   do_final;

  // stage all 32 transfer matrices (15.5 KB)
  {
    const float4* src = reinterpret_cast<const float4*>(Min + (size_t)b * NCH * 121);
    for (int i = tid; i < (NCH * 121) / 4; i += 256)
      reinterpret_cast<float4*>(Ms)[i] = src[i];
  }
  // len partial
  int lp = 0;
  for (int t = tid; t < Sc; t += 256) lp += mask[b * Sc + t];
#pragma unroll
  for (int off = 32; off >= 1; off >>= 1) lp += __shfl_down(lp, off);
  if (lane == 0) ls[wid] = lp;
  __syncthreads();
  if (tid == 0) len_sh = ls[0] + ls[1] + ls[2] + ls[3];
  __syncthreads();
  const int len = len_sh;

  if (wid == 0) {
    // ---- combine: alpha = M_31 o ... o M_0 o alpha0 (all 4 segments duplicate)
    const int ii = (sl < Lc) ? sl : 0;
    float alpha = (sl == START) ? 0.f : NEGC;
#pragma unroll 1
    for (int c = 0; c < NCH; ++c) {
      const float* M = Ms + c * 121;
      float terms[Lc];
      float m = -3.0e38f;
#pragma unroll
      for (int k = 0; k < Lc; k++) {
        const float ak = __shfl(alpha, k, 16);
        terms[k] = M[k * Lc + ii] + ak;
        m = fmaxf(m, terms[k]);
      }
      float s = 0.f;
#pragma unroll
      for (int k = 0; k < Lc; k++) s += exp2f((terms[k] - m) * LOG2E);
      const float anew = m + log2f(s) * LN2;
      alpha = (sl < Lc) ? anew : alpha;
    }
    float v = (sl < Lc) ? (alpha + trans[ENDL * Lc + sl]) : -3.0e38f;
    float mm = v;
#pragma unroll
    for (int off = 8; off >= 1; off >>= 1) mm = fmaxf(mm, __shfl_xor(mm, off, 16));
    float se = exp2f((v - mm) * LOG2E);
#pragma unroll
    for (int off = 8; off >= 1; off >>= 1) se += __shfl_xor(se, off, 16);
    if (lane == 0) norm_sh = mm + log2f(se) * LN2;
  } else {
    // ---- unary + binary over 192 threads
    float u = 0.f;
    for (int t = tid - 64; t < Sc; t += 192)
      if (t < len) u += logits[((size_t)b * Sc + t) * NLc + labels[b * Sc + t]];
    for (int t = tid - 64; t <= Sc; t += 192) {
      if (t <= len) {
        const int cur = (t == 0) ? START : ((t - 1 < len) ? labels[b * Sc + t - 1] : ENDL);
        const int nxt = (t < len) ? labels[b * Sc + t] : ENDL;
        u += trans[nxt * Lc + cur];
      }
    }
#pragma unroll
    for (int off = 32; off >= 1; off >>= 1) u += __shfl_down(u, off);
    if (lane == 0) fs[wid] = u;
  }
  __syncthreads();

  if (tid == 0) {
    const float pb = fs[1] + fs[2] + fs[3] - norm_sh;
    __hip_atomic_store(&part[b], pb, __ATOMIC_RELEASE, __HIP_MEMORY_SCOPE_AGENT);
    const unsigned old = __hip_atomic_fetch_add(cnt, 1u, __ATOMIC_ACQ_REL,
                                                __HIP_MEMORY_SCOPE_AGENT);
    do_final = (old == (unsigned)(Bc - 1)) ? 1 : 0;
  }
  __syncthreads();
  if (do_final && wid == 0) {
    float v = __hip_atomic_load(&part[lane], __ATOMIC_RELAXED,
                                __HIP_MEMORY_SCOPE_AGENT);
#pragma unroll
    for (int off = 32; off >= 1; off >>= 1) v += __shfl_xor(v, off);
    if (lane == 0) out[0] = -v * (1.0f / Bc);
  }
}

extern "C" void kernel_launch(void* const* d_in, const int* in_sizes, int n_in,
                              void* d_out, int out_size, void* d_ws, size_t ws_size,
                              hipStream_t stream)
{
  const float* x      = (const float*)d_in[0];
  const int*   mask   = (const int*)d_in[1];
  const int*   labels = (const int*)d_in[2];
  const float* W      = (const float*)d_in[3];
  const float* bias   = (const float*)d_in[4];
  const float* trans  = (const float*)d_in[5];
  float* out = (float*)d_out;
  float* ws  = (float*)d_ws;

  float*    ws_logits = ws;                                  // B*S*NL floats
  float*    ws_M      = ws_logits + (size_t)Bc * Sc * NLc;   // B*NCH*121 floats
  float*    ws_part   = ws_M + (size_t)Bc * NCH * 121;       // B floats
  unsigned* ws_cnt    = (unsigned*)(ws_part + Bc);           // 1 uint

  hipLaunchKernelGGL(k_logits, dim3(1024), dim3(256), 0, stream, x, W, bias, ws_logits);
  hipLaunchKernelGGL(k_chunk,  dim3(Bc * NCH), dim3(64), 0, stream, ws_logits, mask, trans, ws_M, ws_cnt);
  hipLaunchKernelGGL(k_batch,  dim3(Bc), dim3(256), 0, stream, ws_logits, mask, labels, trans, ws_M, ws_part, ws_cnt, out);
}

// Round 6
// 60.996 us; speedup vs baseline: 3.1459x; 3.1459x over previous
//
#include <hip/hip_runtime.h>

#define Bc 64
#define Sc 512
#define Dc 768
#define NLc 9
#define Lc 11
#define START (Lc-2)
#define ENDL (Lc-1)
#define NEGC -10000.0f
#define LOG2E 1.4426950408889634f
#define LN2 0.6931471805599453f
#define CHUNK 16
#define NCH (Sc / CHUNK)   // 32

// K1: logits[b,s,l] = dot(inputs[b,s,:], W[l,:]) + bias[l]
// 256-thread blocks, grid=1024, (256,4) -> VGPR cap 128 (~70 live, no spill).
// wave = 4 segments of 16 lanes; each wave-pass handles TWO rows per segment
// (rowA = gw*4+seg, rowB = rowA+16384) so each W float4 LDS read feeds both
// rows' FMAs (halves LDS instruction traffic). Depth-2 prefetch via NAMED
// scalars only (round-5 lesson: arrays -> scratch -> 150 MB of spill traffic).
__global__ __launch_bounds__(256, 4) void k_logits(const float* __restrict__ x,
    const float* __restrict__ W, const float* __restrict__ bias,
    float* __restrict__ out)
{
  __shared__ float Wl[NLc * Dc];            // 27648 B
  {
    const float4* Wsrc = reinterpret_cast<const float4*>(W);
    float4* Wdst = reinterpret_cast<float4*>(Wl);
    for (int i = threadIdx.x; i < (NLc * Dc) / 4; i += 256) Wdst[i] = Wsrc[i];
  }
  __syncthreads();
  const int lane = threadIdx.x & 63;
  const int wid  = threadIdx.x >> 6;        // wave in block 0..3
  const int seg  = lane >> 4;               // 0..3
  const int sl   = lane & 15;               // 0..15
  const int gw   = blockIdx.x * 4 + wid;    // global wave id, 0..4095

  const int rowA = gw * 4 + seg;            // 0..16383
  const int rowB = rowA + 16384;
  const float4* xrA = reinterpret_cast<const float4*>(x + (size_t)rowA * Dc);
  const float4* xrB = reinterpret_cast<const float4*>(x + (size_t)rowB * Dc);

  float accA[NLc], accB[NLc];
#pragma unroll
  for (int l = 0; l < NLc; l++) { accA[l] = 0.f; accB[l] = 0.f; }

  // depth-2 pipeline, named scalars
  float4 aC = xrA[sl];            float4 bC = xrB[sl];
  float4 aN = xrA[16 + sl];       float4 bN = xrB[16 + sl];

#pragma unroll
  for (int jj = 0; jj < 6; ++jj) {
    float4 aP, bP, aQ, bQ;
    if (jj < 5) { aP = xrA[(2 * jj + 2) * 16 + sl]; bP = xrB[(2 * jj + 2) * 16 + sl]; }
    {
      const float* wbase = Wl + (2 * jj) * 64 + sl * 4;
#pragma unroll
      for (int l = 0; l < NLc; l++) {
        const float4 wv = *reinterpret_cast<const float4*>(wbase + l * Dc);
        accA[l] = fmaf(aC.x, wv.x, accA[l]);  accB[l] = fmaf(bC.x, wv.x, accB[l]);
        accA[l] = fmaf(aC.y, wv.y, accA[l]);  accB[l] = fmaf(bC.y, wv.y, accB[l]);
        accA[l] = fmaf(aC.z, wv.z, accA[l]);  accB[l] = fmaf(bC.z, wv.z, accB[l]);
        accA[l] = fmaf(aC.w, wv.w, accA[l]);  accB[l] = fmaf(bC.w, wv.w, accB[l]);
      }
    }
    if (jj < 5) { aQ = xrA[(2 * jj + 3) * 16 + sl]; bQ = xrB[(2 * jj + 3) * 16 + sl]; }
    {
      const float* wbase = Wl + (2 * jj + 1) * 64 + sl * 4;
#pragma unroll
      for (int l = 0; l < NLc; l++) {
        const float4 wv = *reinterpret_cast<const float4*>(wbase + l * Dc);
        accA[l] = fmaf(aN.x, wv.x, accA[l]);  accB[l] = fmaf(bN.x, wv.x, accB[l]);
        accA[l] = fmaf(aN.y, wv.y, accA[l]);  accB[l] = fmaf(bN.y, wv.y, accB[l]);
        accA[l] = fmaf(aN.z, wv.z, accA[l]);  accB[l] = fmaf(bN.z, wv.z, accB[l]);
        accA[l] = fmaf(aN.w, wv.w, accA[l]);  accB[l] = fmaf(bN.w, wv.w, accB[l]);
      }
    }
    if (jj < 5) { aC = aP; bC = bP; aN = aQ; bN = bQ; }
  }

  // butterfly reduce within each 16-lane segment (both rows)
#pragma unroll
  for (int off = 8; off >= 1; off >>= 1)
#pragma unroll
    for (int l = 0; l < NLc; l++) {
      accA[l] += __shfl_xor(accA[l], off, 16);
      accB[l] += __shfl_xor(accB[l], off, 16);
    }
  // lane sl (<9) writes label sl -> coalesced 36B store per segment per row
  float vA = accA[0], vB = accB[0];
#pragma unroll
  for (int l = 1; l < NLc; l++) { vA = (sl == l) ? accA[l] : vA; vB = (sl == l) ? accB[l] : vB; }
  if (sl < NLc) {
    const float bb = bias[sl];
    out[(size_t)rowA * NLc + sl] = vA + bb;
    out[(size_t)rowB * NLc + sl] = vB + bb;
  }
}

// Phase 1: per (batch, chunk) compute the 11x11 log-semiring transfer matrix.
// Storage: Mout[(b*NCH+c)*121 + j*11 + i] = M[i][j] (exit i, enter j).
// Also zeroes the k_batch completion counter (block 0) each call.
__global__ __launch_bounds__(64) void k_chunk(const float* __restrict__ logits,
    const int* __restrict__ mask, const float* __restrict__ trans,
    float* __restrict__ Mout, unsigned* __restrict__ cnt)
{
  if (blockIdx.x == 0 && threadIdx.x == 0) cnt[0] = 0u;
  const int b = blockIdx.x / NCH;
  const int c = blockIdx.x % NCH;
  const int lane = threadIdx.x;
  __shared__ float Mbuf[2][121];
  __shared__ float Llog[CHUNK][NLc];

  int len = 0;
  for (int t = lane; t < Sc; t += 64) len += mask[b * Sc + t];
#pragma unroll
  for (int off = 32; off >= 1; off >>= 1) len += __shfl_xor(len, off);

  for (int i = lane; i < CHUNK * NLc; i += 64) {
    const int t = i / NLc, l = i % NLc;
    Llog[t][l] = logits[((size_t)b * Sc + c * CHUNK + t) * NLc + l];
  }
  for (int e = lane; e < 121; e += 64) {
    const int i = e % Lc, j = e / Lc;
    Mbuf[0][e] = (i == j) ? 0.f : NEGC;
  }
  const int e1 = lane;          const bool v1 = (e1 < 121);
  const int e2 = lane + 64;     const bool v2 = (e2 < 121);
  const int i1 = v1 ? (e1 % Lc) : 0, j1 = v1 ? (e1 / Lc) : 0;
  const int i2 = v2 ? (e2 % Lc) : 0, j2 = v2 ? (e2 / Lc) : 0;
  float trow1[Lc], trow2[Lc];
#pragma unroll
  for (int k = 0; k < Lc; k++) {
    trow1[k] = trans[i1 * Lc + k];
    trow2[k] = trans[i2 * Lc + k];
  }
  __syncthreads();

  int p = 0;
  for (int t = 0; t < CHUNK; ++t) {
    const int tg = c * CHUNK + t;
    if (tg < len) {   // uniform across block
      const float lg1 = (i1 < NLc) ? Llog[t][i1] : NEGC;
      const float lg2 = (i2 < NLc) ? Llog[t][i2] : NEGC;
      float terms[Lc];
      float m1 = -3.0e38f;
#pragma unroll
      for (int k = 0; k < Lc; k++) {
        terms[k] = trow1[k] + Mbuf[p][j1 * Lc + k];
        m1 = fmaxf(m1, terms[k]);
      }
      float s1 = 0.f;
#pragma unroll
      for (int k = 0; k < Lc; k++) s1 += exp2f((terms[k] - m1) * LOG2E);
      const float n1 = lg1 + m1 + log2f(s1) * LN2;
      float m2 = -3.0e38f;
#pragma unroll
      for (int k = 0; k < Lc; k++) {
        terms[k] = trow2[k] + Mbuf[p][j2 * Lc + k];
        m2 = fmaxf(m2, terms[k]);
      }
      float s2 = 0.f;
#pragma unroll
      for (int k = 0; k < Lc; k++) s2 += exp2f((terms[k] - m2) * LOG2E);
      const float n2 = lg2 + m2 + log2f(s2) * LN2;
      if (v1) Mbuf[p ^ 1][e1] = n1;
      if (v2) Mbuf[p ^ 1][e2] = n2;
      p ^= 1;
    }
    __syncthreads();
  }
  for (int e = lane; e < 121; e += 64)
    Mout[((size_t)b * NCH + c) * 121 + e] = Mbuf[p][e];
}

// K_batch: per batch -- wave 0 runs the 32-step combine (norm), waves 1-3 do
// unary+binary gathers concurrently; then part[b] = u - norm; the last block
// to finish sums all parts and writes the loss (agent-scope atomics, G16).
__global__ __launch_bounds__(256) void k_batch(const float* __restrict__ logits,
    const int* __restrict__ mask, const int* __restrict__ labels,
    const float* __restrict__ trans, const float* __restrict__ Min,
    float* __restrict__ part, unsigned* __restrict__ cnt,
    float* __restrict__ out)
{
  const int b = blockIdx.x;
  const int tid = threadIdx.x;
  const int wid = tid >> 6;
  const int lane = tid & 63;
  const int sl = lane & 15;
  __shared__ float Ms[NCH * 121];
  __shared__ int   ls[4];
  __shared__ float fs[4];
  __shared__ int   len_sh;
  __shared__ float norm_sh;
  __shared__ int   do_final;

  {
    const float4* src = reinterpret_cast<const float4*>(Min + (size_t)b * NCH * 121);
    for (int i = tid; i < (NCH * 121) / 4; i += 256)
      reinterpret_cast<float4*>(Ms)[i] = src[i];
  }
  int lp = 0;
  for (int t = tid; t < Sc; t += 256) lp += mask[b * Sc + t];
#pragma unroll
  for (int off = 32; off >= 1; off >>= 1) lp += __shfl_down(lp, off);
  if (lane == 0) ls[wid] = lp;
  __syncthreads();
  if (tid == 0) len_sh = ls[0] + ls[1] + ls[2] + ls[3];
  __syncthreads();
  const int len = len_sh;

  if (wid == 0) {
    const int ii = (sl < Lc) ? sl : 0;
    float alpha = (sl == START) ? 0.f : NEGC;
#pragma unroll 1
    for (int c = 0; c < NCH; ++c) {
      const float* M = Ms + c * 121;
      float terms[Lc];
      float m = -3.0e38f;
#pragma unroll
      for (int k = 0; k < Lc; k++) {
        const float ak = __shfl(alpha, k, 16);
        terms[k] = M[k * Lc + ii] + ak;
        m = fmaxf(m, terms[k]);
      }
      float s = 0.f;
#pragma unroll
      for (int k = 0; k < Lc; k++) s += exp2f((terms[k] - m) * LOG2E);
      const float anew = m + log2f(s) * LN2;
      alpha = (sl < Lc) ? anew : alpha;
    }
    float v = (sl < Lc) ? (alpha + trans[ENDL * Lc + sl]) : -3.0e38f;
    float mm = v;
#pragma unroll
    for (int off = 8; off >= 1; off >>= 1) mm = fmaxf(mm, __shfl_xor(mm, off, 16));
    float se = exp2f((v - mm) * LOG2E);
#pragma unroll
    for (int off = 8; off >= 1; off >>= 1) se += __shfl_xor(se, off, 16);
    if (lane == 0) norm_sh = mm + log2f(se) * LN2;
  } else {
    float u = 0.f;
    for (int t = tid - 64; t < Sc; t += 192)
      if (t < len) u += logits[((size_t)b * Sc + t) * NLc + labels[b * Sc + t]];
    for (int t = tid - 64; t <= Sc; t += 192) {
      if (t <= len) {
        const int cur = (t == 0) ? START : ((t - 1 < len) ? labels[b * Sc + t - 1] : ENDL);
        const int nxt = (t < len) ? labels[b * Sc + t] : ENDL;
        u += trans[nxt * Lc + cur];
      }
    }
#pragma unroll
    for (int off = 32; off >= 1; off >>= 1) u += __shfl_down(u, off);
    if (lane == 0) fs[wid] = u;
  }
  __syncthreads();

  if (tid == 0) {
    const float pb = fs[1] + fs[2] + fs[3] - norm_sh;
    __hip_atomic_store(&part[b], pb, __ATOMIC_RELEASE, __HIP_MEMORY_SCOPE_AGENT);
    const unsigned old = __hip_atomic_fetch_add(cnt, 1u, __ATOMIC_ACQ_REL,
                                                __HIP_MEMORY_SCOPE_AGENT);
    do_final = (old == (unsigned)(Bc - 1)) ? 1 : 0;
  }
  __syncthreads();
  if (do_final && wid == 0) {
    float v = __hip_atomic_load(&part[lane], __ATOMIC_RELAXED,
                                __HIP_MEMORY_SCOPE_AGENT);
#pragma unroll
    for (int off = 32; off >= 1; off >>= 1) v += __shfl_xor(v, off);
    if (lane == 0) out[0] = -v * (1.0f / Bc);
  }
}

extern "C" void kernel_launch(void* const* d_in, const int* in_sizes, int n_in,
                              void* d_out, int out_size, void* d_ws, size_t ws_size,
                              hipStream_t stream)
{
  const float* x      = (const float*)d_in[0];
  const int*   mask   = (const int*)d_in[1];
  const int*   labels = (const int*)d_in[2];
  const float* W      = (const float*)d_in[3];
  const float* bias   = (const float*)d_in[4];
  const float* trans  = (const float*)d_in[5];
  float* out = (float*)d_out;
  float* ws  = (float*)d_ws;

  float*    ws_logits = ws;                                  // B*S*NL floats
  float*    ws_M      = ws_logits + (size_t)Bc * Sc * NLc;   // B*NCH*121 floats
  float*    ws_part   = ws_M + (size_t)Bc * NCH * 121;       // B floats
  unsigned* ws_cnt    = (unsigned*)(ws_part + Bc);           // 1 uint

  hipLaunchKernelGGL(k_logits, dim3(1024), dim3(256), 0, stream, x, W, bias, ws_logits);
  hipLaunchKernelGGL(k_chunk,  dim3(Bc * NCH), dim3(64), 0, stream, ws_logits, mask, trans, ws_M, ws_cnt);
  hipLaunchKernelGGL(k_batch,  dim3(Bc), dim3(256), 0, stream, ws_logits, mask, labels, trans, ws_M, ws_part, ws_cnt, out);
}